// Round 1
// baseline (792.177 us; speedup 1.0000x reference)
//
#include <hip/hip_runtime.h>
#include <stdint.h>
#include <stddef.h>

// ---------------- common helpers ----------------

typedef __bf16 bf16x8 __attribute__((ext_vector_type(8)));
typedef float  f32x4  __attribute__((ext_vector_type(4)));

#define MFMA16x16(a,b,c) __builtin_amdgcn_mfma_f32_16x16x32_bf16((a),(b),(c),0,0,0)

__device__ __forceinline__ uint16_t f2bf(float f){
  union { float f; uint32_t u; } v; v.f = f;
  uint32_t u = v.u + 0x7fffu + ((v.u >> 16) & 1u);
  return (uint16_t)(u >> 16);
}
__device__ __forceinline__ float bf2f(uint16_t h){
  union { uint32_t u; float f; } v; v.u = ((uint32_t)h) << 16;
  return v.f;
}
__device__ __forceinline__ bf16x8 load_frag(const uint16_t* p){
  uint4 u = *reinterpret_cast<const uint4*>(p);
  return __builtin_bit_cast(bf16x8, u);
}
__device__ __forceinline__ f32x4 fzero(){
  f32x4 z = {0.f, 0.f, 0.f, 0.f};
  return z;
}

// ---------------- 1) transpose + f32->bf16 convert ----------------
// in: R x C (f32, row-major)  ->  out: C x R (bf16, row-major)
__global__ __launch_bounds__(256) void k_transpose_cvt(const float* __restrict__ in,
                                                       uint16_t* __restrict__ out,
                                                       int R, int C){
  __shared__ float t[32][33];
  const int tc = blockIdx.x * 32;   // C-dim tile
  const int tr = blockIdx.y * 32;   // R-dim tile
  const int j = threadIdx.x & 31, i0 = threadIdx.x >> 5;
  for(int ii = 0; ii < 4; ++ii){
    int r = i0 + ii * 8;
    t[r][j] = in[(size_t)(tr + r) * C + tc + j];
  }
  __syncthreads();
  for(int ii = 0; ii < 4; ++ii){
    int c = i0 + ii * 8;
    out[(size_t)(tc + c) * R + tr + j] = f2bf(t[j][c]);
  }
}

// ---------------- 2) down-proj + RMSNorm (f32), bf16 out ----------------
// x: [4096][1024] f32, w_down: [1024][192] f32, rms_w: [192] f32
// h_out: [4096][192] bf16.  8 tokens per block, 192 threads.
__global__ __launch_bounds__(192) void k_down_rms(const float* __restrict__ x,
                                                  const float* __restrict__ w_down,
                                                  const float* __restrict__ rms_w,
                                                  uint16_t* __restrict__ h_out){
  __shared__ float xs[8][1024];
  __shared__ float hs[8][192];
  __shared__ float sc[8];
  const int j = threadIdx.x;
  const int t0 = blockIdx.x * 8;
  for(int idx = j; idx < 8 * 1024; idx += 192)
    xs[idx >> 10][idx & 1023] = x[(size_t)t0 * 1024 + idx];
  __syncthreads();
  float acc[8] = {0.f,0.f,0.f,0.f,0.f,0.f,0.f,0.f};
  for(int k = 0; k < 1024; ++k){
    float w = w_down[(size_t)k * 192 + j];
#pragma unroll
    for(int t = 0; t < 8; ++t) acc[t] += xs[t][k] * w;
  }
#pragma unroll
  for(int t = 0; t < 8; ++t) hs[t][j] = acc[t];
  __syncthreads();
  if(j < 8){
    float s = 0.f;
    for(int q = 0; q < 192; ++q){ float v = hs[j][q]; s += v * v; }
    sc[j] = rsqrtf(s * (1.0f / 192.0f) + 1e-6f);
  }
  __syncthreads();
  float w = rms_w[j];
#pragma unroll
  for(int t = 0; t < 8; ++t)
    h_out[(size_t)(t0 + t) * 192 + j] = f2bf(hs[t][j] * sc[t] * w);
}

// ---------------- 3) up-proj GEMM (register MFMA, K=192) ----------------
// hmat: [4096][192] bf16, wt: [9216][192] bf16 (w_up^T), qkv: [4096][9216] bf16
// grid (36, 128), block 256: block tile 32m x 256n, each wave 32m x 64n.
__global__ __launch_bounds__(256) void k_gemm_up(const uint16_t* __restrict__ hmat,
                                                 const uint16_t* __restrict__ wt,
                                                 uint16_t* __restrict__ qkv){
  const int wave = threadIdx.x >> 6, lane = threadIdx.x & 63;
  const int ml = lane & 15, qd = lane >> 4;
  const int m0 = blockIdx.y * 32;
  const int n0 = blockIdx.x * 256 + wave * 64;
  bf16x8 af[2][6];
#pragma unroll
  for(int mt = 0; mt < 2; ++mt)
#pragma unroll
    for(int kk = 0; kk < 6; ++kk)
      af[mt][kk] = load_frag(hmat + (size_t)(m0 + mt * 16 + ml) * 192 + kk * 32 + qd * 8);
  f32x4 acc[4][2];
#pragma unroll
  for(int nt = 0; nt < 4; ++nt){ acc[nt][0] = fzero(); acc[nt][1] = fzero(); }
#pragma unroll
  for(int nt = 0; nt < 4; ++nt){
#pragma unroll
    for(int kk = 0; kk < 6; ++kk){
      bf16x8 b = load_frag(wt + (size_t)(n0 + nt * 16 + ml) * 192 + kk * 32 + qd * 8);
      acc[nt][0] = MFMA16x16(af[0][kk], b, acc[nt][0]);
      acc[nt][1] = MFMA16x16(af[1][kk], b, acc[nt][1]);
    }
  }
#pragma unroll
  for(int nt = 0; nt < 4; ++nt)
#pragma unroll
    for(int mt = 0; mt < 2; ++mt)
#pragma unroll
      for(int r = 0; r < 4; ++r){
        int row = m0 + mt * 16 + qd * 4 + r;
        int col = n0 + nt * 16 + ml;
        qkv[(size_t)row * 9216 + col] = f2bf(acc[nt][mt][r]);
      }
}

// ---------------- 4) reorg + RoPE ----------------
// qkv[b,s, which*3072 + d*16 + h]  ->
//   q_t,k_t: [b,h,s,d] (RoPE applied on d in [128,160))
//   v_t:     [b,h,d,s]
// grid (64 s-tiles, 4 d-tiles of 48, 6 = which*2+b), block 256.
__global__ __launch_bounds__(256) void k_reorg(const uint16_t* __restrict__ qkv,
                                               uint16_t* __restrict__ q_t,
                                               uint16_t* __restrict__ k_t,
                                               uint16_t* __restrict__ v_t){
  __shared__ __align__(16) uint16_t t[32][776];
  const int tid = threadIdx.x;
  const int s0 = blockIdx.x * 32;
  const int d0 = blockIdx.y * 48;
  const int which = blockIdx.z >> 1, b = blockIdx.z & 1;
  const size_t inbase = ((size_t)b * 2048 + s0) * 9216 + (size_t)which * 3072 + (size_t)d0 * 16;
  for(int it = 0; it < 12; ++it){
    int idx = it * 256 + tid;           // 32 rows x 96 chunks(16B)
    int ss = idx / 96, c = idx % 96;
    uint4 u = *reinterpret_cast<const uint4*>(qkv + inbase + (size_t)ss * 9216 + c * 8);
    *reinterpret_cast<uint4*>(&t[ss][c * 8]) = u;
  }
  __syncthreads();
  if(which < 2 && d0 >= 96){            // rope dims 128..159 live in d-tiles 96.. and 144..
    const int lo = (d0 == 96) ? 128 : 144;
    for(int it = 0; it < 16; ++it){
      int idx = it * 256 + tid;         // 32 ss * 8 pairs * 16 h = 4096
      int ss = idx >> 7;
      int rem = idx & 127;
      int pi = rem >> 4, hh = rem & 15;
      int de = lo + pi * 2;
      int ce = (de - d0) * 16 + hh;
      float xe = bf2f(t[ss][ce]);
      float xo = bf2f(t[ss][ce + 16]);
      int fi = (de - 128) >> 1;
      float invf = __expf(-(float)fi * 0.5756462732485114f); // ln(10000)/16
      float ang = (float)(s0 + ss) * invf;
      float sn, cs;
      sincosf(ang, &sn, &cs);
      t[ss][ce]      = f2bf(xe * cs - xo * sn);
      t[ss][ce + 16] = f2bf(xo * cs + xe * sn);
    }
    __syncthreads();
  }
  if(which < 2){
    uint16_t* dst = which ? k_t : q_t;
    for(int it = 0; it < 2; ++it){
      int idx = it * 256 + tid;         // 16 h * 32 ss
      int hh = idx & 15, ss = (idx >> 4) & 31;
      size_t ob = (((size_t)b * 16 + hh) * 2048 + (s0 + ss)) * 192 + d0;
      for(int dd = 0; dd < 48; ++dd)
        dst[ob + dd] = t[ss][dd * 16 + hh];
    }
  } else {
    for(int it = 0; it < 3; ++it){
      int idx = it * 256 + tid;         // 16 h * 48 dd
      int hh = idx & 15, dd = idx >> 4;
      size_t ob = (((size_t)b * 16 + hh) * 192 + (d0 + dd)) * 2048 + s0;
      for(int ss = 0; ss < 32; ++ss)
        v_t[ob + ss] = t[ss][dd * 16 + hh];
    }
  }
}

// ---------------- 5) causal flash attention ----------------
// q_t,k_t: [bh][s][192] bf16; v_t: [bh][192][s] bf16; attn_out: [b*2048+s][h*192+d] bf16
// grid (32 q-tiles, 32 bh), block 256 (4 waves x 16 q-rows). K-tile 64.
// LDS tiles use 16B-chunk XOR swizzle: chunk' = chunk ^ (row & 7).
__global__ __launch_bounds__(256) void k_attn(const uint16_t* __restrict__ q_t,
                                              const uint16_t* __restrict__ k_t,
                                              const uint16_t* __restrict__ v_t,
                                              uint16_t* __restrict__ attn_out){
  __shared__ __align__(16) uint16_t ks[64 * 192];
  __shared__ __align__(16) uint16_t vs[192 * 64];
  __shared__ __align__(16) uint16_t ps[4][16 * 64];
  const int tid  = threadIdx.x;
  const int wave = tid >> 6;
  const int lane = tid & 63;
  const int ml   = lane & 15;
  const int qd   = lane >> 4;
  const int qt   = (int)gridDim.x - 1 - (int)blockIdx.x;   // heavy blocks first
  const int bh   = blockIdx.y;
  const int q0   = qt * 64;
  const size_t kbase = (size_t)bh * 2048 * 192;
  const size_t vbase = (size_t)bh * 192 * 2048;

  // stage Q into ks (reused later for K), pull A-frags to registers
  {
    const uint16_t* qsrc = q_t + kbase + (size_t)q0 * 192;
    for(int it = 0; it < 6; ++it){
      int idx = it * 256 + tid;               // 64 rows x 24 chunks
      int row = idx / 24, c = idx % 24;
      uint4 u = *reinterpret_cast<const uint4*>(qsrc + (size_t)row * 192 + c * 8);
      *reinterpret_cast<uint4*>(ks + row * 192 + ((c ^ (row & 7)) * 8)) = u;
    }
  }
  __syncthreads();
  bf16x8 qf[6];
  {
    int row = wave * 16 + ml;
#pragma unroll
    for(int kk = 0; kk < 6; ++kk){
      int c = (kk * 4 + qd) ^ (row & 7);
      qf[kk] = load_frag(ks + row * 192 + c * 8);
    }
  }

  f32x4 o[12];
#pragma unroll
  for(int i = 0; i < 12; ++i) o[i] = fzero();
  float mrow[4] = {-3e38f, -3e38f, -3e38f, -3e38f};
  float lrow[4] = {0.f, 0.f, 0.f, 0.f};
  const float scale = 0.07216878364870322f;   // 1/sqrt(192)

  const int ktiles = qt + 1;
  for(int kt = 0; kt < ktiles; ++kt){
    __syncthreads();                           // prior reads of ks/vs/ps done
    for(int it = 0; it < 6; ++it){             // stage K tile [64][192]
      int idx = it * 256 + tid;
      int row = idx / 24, c = idx % 24;
      uint4 u = *reinterpret_cast<const uint4*>(k_t + kbase + (size_t)(kt * 64 + row) * 192 + c * 8);
      *reinterpret_cast<uint4*>(ks + row * 192 + ((c ^ (row & 7)) * 8)) = u;
    }
    for(int it = 0; it < 6; ++it){             // stage V^T tile [192][64]
      int idx = it * 256 + tid;
      int d = idx >> 3, c = idx & 7;
      uint4 u = *reinterpret_cast<const uint4*>(v_t + vbase + (size_t)d * 2048 + kt * 64 + c * 8);
      *reinterpret_cast<uint4*>(vs + d * 64 + ((c ^ (d & 7)) * 8)) = u;
    }
    __syncthreads();

    // S = Q K^T (per wave: 16 q-rows x 64 keys)
    f32x4 s4[4];
#pragma unroll
    for(int nt = 0; nt < 4; ++nt){
      f32x4 a = fzero();
      int row = nt * 16 + ml;
#pragma unroll
      for(int kk = 0; kk < 6; ++kk){
        int c = (kk * 4 + qd) ^ (row & 7);
        bf16x8 b = load_frag(ks + row * 192 + c * 8);
        a = MFMA16x16(qf[kk], b, a);
      }
      s4[nt] = a;
    }

    const bool diag = (kt == qt);
    float pv[4][4];
#pragma unroll
    for(int nt = 0; nt < 4; ++nt)
#pragma unroll
      for(int r = 0; r < 4; ++r){
        float v = s4[nt][r] * scale;
        if(diag){
          int i = q0 + wave * 16 + qd * 4 + r;
          int j = kt * 64 + nt * 16 + ml;
          if(j > i) v = -1e9f;
        }
        pv[nt][r] = v;
      }

    float alpha[4];
#pragma unroll
    for(int r = 0; r < 4; ++r){
      float mx = fmaxf(fmaxf(pv[0][r], pv[1][r]), fmaxf(pv[2][r], pv[3][r]));
#pragma unroll
      for(int off = 1; off < 16; off <<= 1)
        mx = fmaxf(mx, __shfl_xor(mx, off));
      float mn = fmaxf(mrow[r], mx);
      alpha[r] = __expf(mrow[r] - mn);
      mrow[r] = mn;
    }
#pragma unroll
    for(int r = 0; r < 4; ++r){
      float rs = 0.f;
#pragma unroll
      for(int nt = 0; nt < 4; ++nt){
        float e = __expf(pv[nt][r] - mrow[r]);
        pv[nt][r] = e;
        rs += e;
      }
#pragma unroll
      for(int off = 1; off < 16; off <<= 1)
        rs += __shfl_xor(rs, off);
      lrow[r] = lrow[r] * alpha[r] + rs;
    }
#pragma unroll
    for(int dt = 0; dt < 12; ++dt){
      o[dt][0] *= alpha[0]; o[dt][1] *= alpha[1];
      o[dt][2] *= alpha[2]; o[dt][3] *= alpha[3];
    }
    // P (C-layout) -> LDS bf16 (A-layout readback)
#pragma unroll
    for(int nt = 0; nt < 4; ++nt)
#pragma unroll
      for(int r = 0; r < 4; ++r){
        int rp = qd * 4 + r;
        int col = nt * 16 + ml;
        int c = (col >> 3) ^ (rp & 7);
        ps[wave][rp * 64 + c * 8 + (col & 7)] = f2bf(pv[nt][r]);
      }
    __syncthreads();
    // O += P V
#pragma unroll
    for(int kk2 = 0; kk2 < 2; ++kk2){
      int cp = (kk2 * 4 + qd) ^ (ml & 7);
      bf16x8 pa = load_frag(&ps[wave][ml * 64 + cp * 8]);
#pragma unroll
      for(int dt = 0; dt < 12; ++dt){
        int row = dt * 16 + ml;
        int cv = (kk2 * 4 + qd) ^ (row & 7);
        bf16x8 vb = load_frag(vs + row * 64 + cv * 8);
        o[dt] = MFMA16x16(pa, vb, o[dt]);
      }
    }
  }

  const int hh = bh & 15, b = bh >> 4;
#pragma unroll
  for(int r = 0; r < 4; ++r){
    int i = q0 + wave * 16 + qd * 4 + r;
    float inv = 1.0f / lrow[r];
    size_t obase = ((size_t)b * 2048 + i) * 3072 + hh * 192;
#pragma unroll
    for(int dt = 0; dt < 12; ++dt)
      attn_out[obase + dt * 16 + ml] = f2bf(o[dt][r] * inv);
  }
}

// ---------------- 6) out-proj GEMM (register MFMA, K=3072) ----------------
// a: [4096][3072] bf16, wt: [1024][3072] bf16 (w_o^T), out: [4096][1024] f32
// grid (8, 64), block 256: block tile 64m x 128n, wave 32m x 64n.
__global__ __launch_bounds__(256) void k_gemm_o(const uint16_t* __restrict__ a,
                                                const uint16_t* __restrict__ wt,
                                                float* __restrict__ out){
  const int wave = threadIdx.x >> 6, lane = threadIdx.x & 63;
  const int ml = lane & 15, qd = lane >> 4;
  const int m0 = blockIdx.y * 64 + (wave >> 1) * 32;
  const int n0 = blockIdx.x * 128 + (wave & 1) * 64;
  f32x4 acc[2][4];
#pragma unroll
  for(int mt = 0; mt < 2; ++mt)
#pragma unroll
    for(int nt = 0; nt < 4; ++nt) acc[mt][nt] = fzero();
  for(int kk = 0; kk < 96; ++kk){
    bf16x8 af[2], bfr[4];
#pragma unroll
    for(int mt = 0; mt < 2; ++mt)
      af[mt] = load_frag(a + (size_t)(m0 + mt * 16 + ml) * 3072 + kk * 32 + qd * 8);
#pragma unroll
    for(int nt = 0; nt < 4; ++nt)
      bfr[nt] = load_frag(wt + (size_t)(n0 + nt * 16 + ml) * 3072 + kk * 32 + qd * 8);
#pragma unroll
    for(int mt = 0; mt < 2; ++mt)
#pragma unroll
      for(int nt = 0; nt < 4; ++nt)
        acc[mt][nt] = MFMA16x16(af[mt], bfr[nt], acc[mt][nt]);
  }
#pragma unroll
  for(int mt = 0; mt < 2; ++mt)
#pragma unroll
    for(int nt = 0; nt < 4; ++nt)
#pragma unroll
      for(int r = 0; r < 4; ++r){
        int row = m0 + mt * 16 + qd * 4 + r;
        int col = n0 + nt * 16 + ml;
        out[(size_t)row * 1024 + col] = acc[mt][nt][r];
      }
}

// ---------------- launch ----------------

extern "C" void kernel_launch(void* const* d_in, const int* in_sizes, int n_in,
                              void* d_out, int out_size, void* d_ws, size_t ws_size,
                              hipStream_t stream) {
  (void)in_sizes; (void)n_in; (void)out_size; (void)ws_size;
  const float* x      = (const float*)d_in[0];
  // d_in[1] = mask (int32) — causal, handled analytically
  const float* w_down = (const float*)d_in[2];
  const float* rms_w  = (const float*)d_in[3];
  const float* w_up   = (const float*)d_in[4];
  const float* w_o    = (const float*)d_in[5];
  float* out = (float*)d_out;

  char* ws = (char*)d_ws;
  uint16_t* h_bf   = (uint16_t*)(ws);                     // 4096*192       = 1,572,864 B
  uint16_t* w_up_t = (uint16_t*)(ws + 1572864);           // 9216*192       = 3,538,944 B
  uint16_t* w_o_t  = (uint16_t*)(ws + 5111808);           // 1024*3072      = 6,291,456 B
  uint16_t* q_tb   = (uint16_t*)(ws + 11403264);          // 32*2048*192    = 25,165,824 B
  uint16_t* k_tb   = (uint16_t*)(ws + 36569088);          // 25,165,824 B
  uint16_t* v_tb   = (uint16_t*)(ws + 61734912);          // 25,165,824 B
  uint16_t* qkv    = (uint16_t*)(ws + 86900736);          // 4096*9216      = 75,497,472 B
  uint16_t* attnO  = qkv;                                 // alias: qkv dead after reorg

  k_transpose_cvt<<<dim3(288, 6), 256, 0, stream>>>(w_up, w_up_t, 192, 9216);
  k_transpose_cvt<<<dim3(32, 96), 256, 0, stream>>>(w_o,  w_o_t,  3072, 1024);
  k_down_rms<<<512, 192, 0, stream>>>(x, w_down, rms_w, h_bf);
  k_gemm_up<<<dim3(36, 128), 256, 0, stream>>>(h_bf, w_up_t, qkv);
  k_reorg<<<dim3(64, 4, 6), 256, 0, stream>>>(qkv, q_tb, k_tb, v_tb);
  k_attn<<<dim3(32, 32), 256, 0, stream>>>(q_tb, k_tb, v_tb, attnO);
  k_gemm_o<<<dim3(8, 64), 256, 0, stream>>>(attnO, w_o_t, out);
}